// Round 1
// baseline (387.886 us; speedup 1.0000x reference)
//
#include <hip/hip_runtime.h>

// FwFM: out[b] = w0 + sum_f bias[x[b,f]] + 0.5 * sum_{i!=j} W[i,j] * <e_i, e_j>
// One block per sample. E rows gathered to LDS (stride 68 floats to break bank
// conflicts), W staged to LDS with diagonal zeroed and rows padded to 48 so the
// 16x3 i-tiling is branch-free. Thread (g,h) owns i in {3g..3g+2}, c in [4h,4h+4).

constexpr int NF   = 39;   // fields
constexpr int D    = 64;   // embed dim
constexpr int IPAD = 48;   // i padded to 16 groups * 3
constexpr int EST  = D + 4; // LDS row stride in floats (68: float4-aligned, odd*4 banks)
constexpr int NT   = 256;

__global__ __launch_bounds__(NT) void fwfm_kernel(
    const int*   __restrict__ x,     // (B, 39) int32
    const float* __restrict__ emb,   // (1e6, 64)
    const float* __restrict__ bias,  // (1e6, 1)
    const float* __restrict__ W,     // (39, 39)
    const float* __restrict__ w0,    // (1,)
    float*       __restrict__ out)   // (B,)
{
    __shared__ float sE[IPAD * EST];   // 13056 B
    __shared__ float sW[IPAD * NF];    // 7488 B, diag zeroed, rows 39..47 zero
    __shared__ int   sIdx[NF];
    __shared__ float sRed[NT / 64];

    const int b = blockIdx.x;
    const int t = threadIdx.x;

    if (t < NF) sIdx[t] = x[(size_t)b * NF + t];

    // Stage W with zeroed diagonal; zero the padded i-rows.
    for (int u = t; u < IPAD * NF; u += NT) {
        int i = u / NF;
        int j = u - i * NF;
        sW[u] = (i < NF && i != j) ? W[i * NF + j] : 0.0f;
    }
    // Zero padded E rows (avoid NaN garbage hitting 0*NaN in pad lanes).
    for (int u = t; u < (IPAD - NF) * 16; u += NT) {
        int r = NF + (u >> 4), c = u & 15;
        *(float4*)(sE + r * EST + c * 4) = make_float4(0.f, 0.f, 0.f, 0.f);
    }
    __syncthreads();

    // Gather 39 embedding rows (256 B each, coalesced: 16 lanes per row).
    for (int u = t; u < NF * 16; u += NT) {
        int r = u >> 4, c = u & 15;
        const float4* src = (const float4*)(emb + (size_t)sIdx[r] * D);
        *(float4*)(sE + r * EST + c * 4) = src[c];
    }
    float bsum = (t < NF) ? bias[(size_t)sIdx[t]] : 0.0f;
    __syncthreads();

    // Compute: thread (g,h) accumulates over all j for its 3 i's and 4 d's.
    const int g  = t >> 4;        // 0..15
    const int h  = t & 15;        // 0..15
    const int i0 = g * 3;         // 0..45
    const float4 e0 = *(const float4*)(sE + (i0 + 0) * EST + h * 4);
    const float4 e1 = *(const float4*)(sE + (i0 + 1) * EST + h * 4);
    const float4 e2 = *(const float4*)(sE + (i0 + 2) * EST + h * 4);

    float acc = 0.0f;
    #pragma unroll 3
    for (int j = 0; j < NF; ++j) {
        const float4 ej = *(const float4*)(sE + j * EST + h * 4);
        const float w0v = sW[(i0 + 0) * NF + j];
        const float w1v = sW[(i0 + 1) * NF + j];
        const float w2v = sW[(i0 + 2) * NF + j];
        float d0 = ej.x * e0.x + ej.y * e0.y + ej.z * e0.z + ej.w * e0.w;
        float d1 = ej.x * e1.x + ej.y * e1.y + ej.z * e1.z + ej.w * e1.w;
        float d2 = ej.x * e2.x + ej.y * e2.y + ej.z * e2.z + ej.w * e2.w;
        acc = fmaf(w0v, d0, acc);
        acc = fmaf(w1v, d1, acc);
        acc = fmaf(w2v, d2, acc);
    }
    acc = 0.5f * acc + bsum;

    // Block reduction: wave64 shuffle, then cross-wave via LDS.
    #pragma unroll
    for (int off = 32; off > 0; off >>= 1)
        acc += __shfl_down(acc, off, 64);
    if ((t & 63) == 0) sRed[t >> 6] = acc;
    __syncthreads();
    if (t == 0) {
        float tot = 0.0f;
        #pragma unroll
        for (int wv = 0; wv < NT / 64; ++wv) tot += sRed[wv];
        out[b] = w0[0] + tot;
    }
}

extern "C" void kernel_launch(void* const* d_in, const int* in_sizes, int n_in,
                              void* d_out, int out_size, void* d_ws, size_t ws_size,
                              hipStream_t stream) {
    const int*   x    = (const int*)d_in[0];
    const float* emb  = (const float*)d_in[1];
    const float* bias = (const float*)d_in[2];
    const float* W    = (const float*)d_in[3];
    const float* w0   = (const float*)d_in[4];
    float*       out  = (float*)d_out;

    const int batch = out_size;  // 16384
    fwfm_kernel<<<batch, NT, 0, stream>>>(x, emb, bias, W, w0, out);
}

// Round 2
// 386.067 us; speedup vs baseline: 1.0047x; 1.0047x over previous
//
#include <hip/hip_runtime.h>

// FwFM, wave-per-sample, LDS-free formulation:
//   inter[b] = 0.5 * sum_d ( E_d^T W' E_d ),  E = gathered (39 x 64) rows,
// lane = d. Lane l holds E[:, l] in 39 VGPRs via 39 fully-coalesced 256B row
// loads (the gather IS the transpose). W' (diag-zeroed, row-padded to 40) is
// wave-uniform -> scalar loads (K$) -> SGPR operand of v_fmac_f32. No LDS.
// q_l = sum_j E[j,l] * (sum_i W'[j][i] * E[i,l]); inter = 0.5 * wave_sum(q).
// (Valid because E_i E_j is symmetric, so using W rows == using W columns.)

constexpr int NF = 39;
constexpr int D  = 64;
constexpr int WP = 40;            // padded W row stride (floats), 160B rows
constexpr int WAVES_PER_BLOCK = 4;
constexpr int NT = 64 * WAVES_PER_BLOCK;

__global__ __launch_bounds__(256) void prep_w(const float* __restrict__ W,
                                              float* __restrict__ Wp) {
    int t = blockIdx.x * blockDim.x + threadIdx.x;
    if (t < WP * WP) {
        int j = t / WP, i = t - j * WP;
        float v = 0.0f;
        if (i < NF && j < NF && i != j) v = W[j * NF + i];
        Wp[t] = v;
    }
}

__global__ __launch_bounds__(NT) void fwfm_kernel(
    const int*   __restrict__ x,     // (B, 39)
    const float* __restrict__ emb,   // (1e6, 64)
    const float* __restrict__ bias,  // (1e6, 1)
    const float* __restrict__ Wp,    // (40, 40) diag-zeroed, padded
    const float* __restrict__ w0,    // (1,)
    float*       __restrict__ out)   // (B,)
{
    const int lane = threadIdx.x & 63;
    // Force wave id onto the scalar path so x/W/bias addressing stays uniform.
    const int wave = __builtin_amdgcn_readfirstlane((int)(threadIdx.x >> 6));
    const int b    = blockIdx.x * WAVES_PER_BLOCK + wave;

    const int* xrow = x + (size_t)b * NF;

    // Field indices: uniform -> SGPRs.
    int idx[NF];
    #pragma unroll
    for (int f = 0; f < NF; ++f) idx[f] = xrow[f];

    // 39 coalesced 256B row loads, one float per lane. All independent ->
    // deep vmcnt pipeline (good MLP on the random gather).
    float E[NF];
    #pragma unroll
    for (int f = 0; f < NF; ++f)
        E[f] = emb[(size_t)idx[f] * D + lane];

    // Bias sum: uniform scalar loads, redundantly accumulated on all lanes.
    float bsum = 0.0f;
    #pragma unroll
    for (int f = 0; f < NF; ++f) bsum += bias[idx[f]];

    // Per-lane quadratic form q = E^T W' E (diag already zero in Wp).
    float q = 0.0f;
    #pragma unroll
    for (int j = 0; j < NF; ++j) {
        const float* wr = Wp + j * WP;   // uniform row -> s_load stream
        float s0 = 0.0f, s1 = 0.0f, s2 = 0.0f, s3 = 0.0f;
        #pragma unroll
        for (int i = 0; i < 36; i += 4) {
            s0 = fmaf(wr[i + 0], E[i + 0], s0);
            s1 = fmaf(wr[i + 1], E[i + 1], s1);
            s2 = fmaf(wr[i + 2], E[i + 2], s2);
            s3 = fmaf(wr[i + 3], E[i + 3], s3);
        }
        s0 = fmaf(wr[36], E[36], s0);
        s1 = fmaf(wr[37], E[37], s1);
        s2 = fmaf(wr[38], E[38], s2);
        q  = fmaf(E[j], (s0 + s1) + (s2 + s3), q);
    }

    // Wave reduction over lanes (= sum over d).
    #pragma unroll
    for (int off = 32; off > 0; off >>= 1)
        q += __shfl_down(q, off, 64);

    if (lane == 0)
        out[b] = w0[0] + bsum + 0.5f * q;
}

extern "C" void kernel_launch(void* const* d_in, const int* in_sizes, int n_in,
                              void* d_out, int out_size, void* d_ws, size_t ws_size,
                              hipStream_t stream) {
    const int*   x    = (const int*)d_in[0];
    const float* emb  = (const float*)d_in[1];
    const float* bias = (const float*)d_in[2];
    const float* W    = (const float*)d_in[3];
    const float* w0   = (const float*)d_in[4];
    float*       out  = (float*)d_out;
    float*       Wp   = (float*)d_ws;   // 40*40*4 = 6.4 KB

    prep_w<<<(WP * WP + 255) / 256, 256, 0, stream>>>(W, Wp);

    const int batch = out_size;  // 16384
    fwfm_kernel<<<batch / WAVES_PER_BLOCK, NT, 0, stream>>>(x, emb, bias, Wp, w0, out);
}

// Round 3
// 358.763 us; speedup vs baseline: 1.0812x; 1.0761x over previous
//
#include <hip/hip_runtime.h>

// FwFM, wave-per-sample, LDS-free:
//   out[b] = w0 + sum_f bias[x_bf] + sum_{i<j} Ws[i,j] * <e_i, e_j>
// with Ws = 0.5*(W + W^T) strict-upper (diag dropped), built once in prep.
// Lane = embedding dim d. Lane l holds E[:, l] via 39 fully-coalesced 256B row
// loads (the gather IS the transpose). Ws is wave-uniform -> scalar loads (K$)
// -> SGPR operand of v_fmac_f32. 780 FMAs/wave (triangular), no LDS.

constexpr int NF = 39;
constexpr int D  = 64;
constexpr int WP = 40;            // padded Ws row stride (floats)
constexpr int WAVES_PER_BLOCK = 4;
constexpr int NT = 64 * WAVES_PER_BLOCK;

__global__ __launch_bounds__(256) void prep_w(const float* __restrict__ W,
                                              float* __restrict__ Ws) {
    int t = blockIdx.x * blockDim.x + threadIdx.x;
    if (t < WP * WP) {
        int i = t / WP, j = t - i * WP;
        float v = 0.0f;
        if (i < NF && j < NF && i < j)
            v = 0.5f * (W[i * NF + j] + W[j * NF + i]);
        Ws[t] = v;
    }
}

__global__ __launch_bounds__(NT) void fwfm_kernel(
    const int*   __restrict__ x,     // (B, 39)
    const float* __restrict__ emb,   // (1e6, 64)
    const float* __restrict__ bias,  // (1e6, 1)
    const float* __restrict__ Ws,    // (40, 40) strict-upper, pre-scaled by 0.5
    const float* __restrict__ w0,    // (1,)
    float*       __restrict__ out)   // (B,)
{
    const int lane = threadIdx.x & 63;
    const int wave = __builtin_amdgcn_readfirstlane((int)(threadIdx.x >> 6));
    const int b    = blockIdx.x * WAVES_PER_BLOCK + wave;

    const int* xrow = x + (size_t)b * NF;

    // Field indices: uniform -> SGPRs.
    int idx[NF];
    #pragma unroll
    for (int f = 0; f < NF; ++f) idx[f] = xrow[f];

    // 39 independent, fully-coalesced 256B row loads (1 float/lane).
    float E[NF];
    #pragma unroll
    for (int f = 0; f < NF; ++f)
        E[f] = emb[(size_t)idx[f] * D + lane];

    // Bias sum: uniform scalar loads, overlaps with the vector gather.
    float bsum = 0.0f;
    #pragma unroll
    for (int f = 0; f < NF; ++f) bsum += bias[idx[f]];

    // Triangular weighted pair-sum: q = sum_j E_j * sum_{i<j} Ws[i][j]*E_i.
    float q = 0.0f;
    #pragma unroll
    for (int j = 1; j < NF; ++j) {
        float s0 = 0.0f, s1 = 0.0f;
        #pragma unroll
        for (int i = 0; i + 1 < j; i += 2) {
            s0 = fmaf(Ws[i * WP + j],       E[i],     s0);
            s1 = fmaf(Ws[(i + 1) * WP + j], E[i + 1], s1);
        }
        if (j & 1) s0 = fmaf(Ws[(j - 1) * WP + j], E[j - 1], s0);
        q = fmaf(E[j], s0 + s1, q);
    }

    // Wave reduction over lanes (= sum over d).
    #pragma unroll
    for (int off = 32; off > 0; off >>= 1)
        q += __shfl_down(q, off, 64);

    if (lane == 0)
        out[b] = w0[0] + bsum + q;
}

extern "C" void kernel_launch(void* const* d_in, const int* in_sizes, int n_in,
                              void* d_out, int out_size, void* d_ws, size_t ws_size,
                              hipStream_t stream) {
    const int*   x    = (const int*)d_in[0];
    const float* emb  = (const float*)d_in[1];
    const float* bias = (const float*)d_in[2];
    const float* W    = (const float*)d_in[3];
    const float* w0   = (const float*)d_in[4];
    float*       out  = (float*)d_out;
    float*       Ws   = (float*)d_ws;   // 40*40*4 = 6.4 KB

    prep_w<<<(WP * WP + 255) / 256, 256, 0, stream>>>(W, Ws);

    const int batch = out_size;  // 16384
    fwfm_kernel<<<batch / WAVES_PER_BLOCK, NT, 0, stream>>>(x, emb, bias, Ws, w0, out);
}

// Round 4
// 353.920 us; speedup vs baseline: 1.0960x; 1.0137x over previous
//
#include <hip/hip_runtime.h>

// FwFM, wave-per-sample, LDS-free:
//   out[b] = w0 + sum_f bias[x_bf] + sum_{i<j} Ws[i,j] * <e_i, e_j>
// Ws = 0.5*(W + W^T), strict upper triangle, PACKED j-major into 741 contiguous
// floats (tri(j)=j(j-1)/2) by the prep kernel. After full unroll every Ws access
// is a compile-time constant offset into a contiguous 2.9KB array -> the
// compiler merges them into s_load_dwordx16 streams (vs 780 strided
// s_load_dword in the previous column-indexed version).
// Lane = embedding dim d; lane l holds E[:, l] via 39 fully-coalesced 256B row
// loads (the gather IS the transpose). No LDS anywhere.

constexpr int NF = 39;
constexpr int D  = 64;
constexpr int NPAIR = NF * (NF - 1) / 2;   // 741
constexpr int WAVES_PER_BLOCK = 4;
constexpr int NT = 64 * WAVES_PER_BLOCK;

__global__ __launch_bounds__(256) void prep_w(const float* __restrict__ W,
                                              float* __restrict__ P) {
    int t = blockIdx.x * blockDim.x + threadIdx.x;
    if (t >= NPAIR) return;
    // invert tri(j) = j(j-1)/2 <= t
    int j = (int)((1.0f + sqrtf(1.0f + 8.0f * (float)t)) * 0.5f);
    while (j > 1 && j * (j - 1) / 2 > t) --j;
    while ((j + 1) * j / 2 <= t) ++j;
    int i = t - j * (j - 1) / 2;           // i < j
    P[t] = 0.5f * (W[i * NF + j] + W[j * NF + i]);
}

__global__ __launch_bounds__(NT) void fwfm_kernel(
    const int*   __restrict__ x,     // (B, 39)
    const float* __restrict__ emb,   // (1e6, 64)
    const float* __restrict__ bias,  // (1e6, 1)
    const float* __restrict__ P,     // (741,) packed sym pair weights
    const float* __restrict__ w0,    // (1,)
    float*       __restrict__ out)   // (B,)
{
    const int lane = threadIdx.x & 63;
    const int wave = __builtin_amdgcn_readfirstlane((int)(threadIdx.x >> 6));
    const int b    = blockIdx.x * WAVES_PER_BLOCK + wave;

    const int* xrow = x + (size_t)b * NF;

    // Field indices: wave-uniform -> SGPRs.
    int idx[NF];
    #pragma unroll
    for (int f = 0; f < NF; ++f) idx[f] = xrow[f];

    // 39 independent, fully-coalesced 256B row loads (1 float/lane).
    float E[NF];
    #pragma unroll
    for (int f = 0; f < NF; ++f)
        E[f] = emb[(size_t)idx[f] * D + lane];

    // Bias sum: uniform scalar loads, overlaps with the vector gather.
    float bsum = 0.0f;
    #pragma unroll
    for (int f = 0; f < NF; ++f) bsum += bias[idx[f]];

    // Triangular weighted pair-sum: q = sum_j E_j * sum_{i<j} P[tri(j)+i]*E_i.
    float q = 0.0f;
    #pragma unroll
    for (int j = 1; j < NF; ++j) {
        const int base = j * (j - 1) / 2;  // compile-time after unroll
        float s0 = 0.0f, s1 = 0.0f;
        #pragma unroll
        for (int i = 0; i + 1 < j; i += 2) {
            s0 = fmaf(P[base + i],     E[i],     s0);
            s1 = fmaf(P[base + i + 1], E[i + 1], s1);
        }
        if (j & 1) s0 = fmaf(P[base + j - 1], E[j - 1], s0);
        q = fmaf(E[j], s0 + s1, q);
    }

    // Wave reduction over lanes (= sum over d).
    #pragma unroll
    for (int off = 32; off > 0; off >>= 1)
        q += __shfl_down(q, off, 64);

    if (lane == 0)
        out[b] = w0[0] + bsum + q;
}

extern "C" void kernel_launch(void* const* d_in, const int* in_sizes, int n_in,
                              void* d_out, int out_size, void* d_ws, size_t ws_size,
                              hipStream_t stream) {
    const int*   x    = (const int*)d_in[0];
    const float* emb  = (const float*)d_in[1];
    const float* bias = (const float*)d_in[2];
    const float* W    = (const float*)d_in[3];
    const float* w0   = (const float*)d_in[4];
    float*       out  = (float*)d_out;
    float*       P    = (float*)d_ws;   // 741 * 4 B

    prep_w<<<(NPAIR + 255) / 256, 256, 0, stream>>>(W, P);

    const int batch = out_size;  // 16384
    fwfm_kernel<<<batch / WAVES_PER_BLOCK, NT, 0, stream>>>(x, emb, bias, P, w0, out);
}